// Round 16
// baseline (248.284 us; speedup 1.0000x reference)
//
#include <hip/hip_runtime.h>

#define N_NODES 1024
#define E_EDGES 524288
#define FE 64
#define FC 128
#define NLAYERS 3

typedef unsigned short u16;
typedef unsigned int u32;
typedef __attribute__((ext_vector_type(8))) short bf16x8;   // MFMA A/B frag
typedef __attribute__((ext_vector_type(4))) float f32x4;    // MFMA C/D frag
typedef __attribute__((ext_vector_type(8))) unsigned short u16x8;
typedef __attribute__((ext_vector_type(4))) unsigned int u32x4;

__device__ __forceinline__ float bf2f(u16 u) {
    return __uint_as_float(((u32)u) << 16);
}
__device__ __forceinline__ u32 cvt2bf(float lo, float hi) {
    u32 r;
    asm("v_cvt_pk_bf16_f32 %0, %1, %2" : "=v"(r) : "v"(lo), "v"(hi));
    return r;
}
__device__ __forceinline__ u16 f2bf(float f) {
    return (u16)cvt2bf(f, 0.f);
}

// ---------------------------------------------------------------------------
// Setup (1024 blocks, one per node): zero S row, copy node->nodeA, transpose
// W_fij into bf16 Wt (blocks 0..47), and layer-0 projections fni/fnj/h.
// ---------------------------------------------------------------------------
__global__ __launch_bounds__(256) void setup_kernel(
    const float* __restrict__ node_feature, const float* __restrict__ Wfij,
    u16* __restrict__ Wt,
    const float* __restrict__ Wni, const float* __restrict__ Wnj,
    const float* __restrict__ Wnode, const float* __restrict__ bias,
    u16* __restrict__ fni, u16* __restrict__ fnj,
    u16* __restrict__ h, float* __restrict__ S, float* __restrict__ nodeA)
{
    __shared__ float row[FC];
    const int d = blockIdx.x;
    const int t = threadIdx.x;

    reinterpret_cast<float4*>(S + (size_t)d * N_NODES)[t] = make_float4(0.f, 0.f, 0.f, 0.f);

    if (t < FC) {
        const float v = node_feature[d * FC + t];
        nodeA[d * FC + t] = v;
        row[t] = v;
    }
    if (d < (NLAYERS * FE * FE) / 256) {
        const int i = d * 256 + t;
        const int l = i >> 12, rem = i & 4095;
        const int n = rem >> 6, k = rem & 63;
        Wt[(u32)(l * 4096 + n * 64 + k)] = f2bf(Wfij[(u32)(l * 4096 + k * 64 + n)]);
    }
    __syncthreads();

    if (t < 64) {
        float a0 = 0.f, a1 = 0.f;
        #pragma unroll 8
        for (int k = 0; k < FC; k += 2) {
            a0 = fmaf(row[k],     Wni[k * FE + t], a0);
            a1 = fmaf(row[k + 1], Wni[(k + 1) * FE + t], a1);
        }
        fni[d * FE + t] = f2bf(a0 + a1);
    } else if (t < 128) {
        const int f = t - 64;
        float a0 = 0.f, a1 = 0.f;
        #pragma unroll 8
        for (int k = 0; k < FC; k += 2) {
            a0 = fmaf(row[k],     Wnj[k * FE + f], a0);
            a1 = fmaf(row[k + 1], Wnj[(k + 1) * FE + f], a1);
        }
        fnj[d * FE + f] = f2bf(a0 + a1);
    } else {
        const int c = t - 128;
        float a0 = bias[c], a1 = 0.f;
        #pragma unroll 8
        for (int k = 0; k < FC; k += 2) {
            a0 = fmaf(row[k],     Wnode[k * FC + c], a0);
            a1 = fmaf(row[k + 1], Wnode[(k + 1) * FC + c], a1);
        }
        h[d * FC + c] = f2bf(a0 + a1);
    }
}

// ---------------------------------------------------------------------------
// MFMA edge kernel, 2-TILE with DOUBLE-BUFFERED stage/fol (r16). r15's
// serialized tile loop left tile1's DS/MFMA stuck behind tile0's epilogue
// via the wave_barriers; with stage[2]/fol[2] both tiles' stage writes and
// MFMAs issue before a single handoff barrier, giving the scheduler a full
// second tile of independent work to hide tile0's dependency stalls.
// Register state unchanged vs r15 (VGPR 60; 4-tile spilled at the 64-VGPR
// allocator ceiling — r14). sidx/didx shuffles exec-full (r11 lesson).
// Fragment layouts (m89 family):
//   A: row=lane&15 (edge), k=(lane>>4)*8+j     B: col=lane&15 (n), same k
//   C: col=lane&15 (n),  row=(lane>>4)*4+reg   (edge)
// ---------------------------------------------------------------------------
template <bool FIRST, bool WRITE_EF>
__global__ void edge_mfma_kernel(
    u16* __restrict__ ef,                 // [E][64] bf16 (in/out)
    const float* __restrict__ x,          // [E][2]   (FIRST only)
    const float* __restrict__ Win,        // [2][64]  (FIRST only)
    const float* __restrict__ bin,        // [64]     (FIRST only)
    const u16* __restrict__ Wt,           // [64 n][64 k] bf16 (this layer)
    const u16* __restrict__ fni, const u16* __restrict__ fnj,
    const int* __restrict__ src, const int* __restrict__ dst,
    const float* __restrict__ attn,       // [64] fp32
    float* __restrict__ S)                // [N][N] fp32 (pre-zeroed)
{
    __shared__ __align__(16) u16 stage[2][4][16][72];               // per-tile
    __shared__ __align__(16) u16 fol[WRITE_EF ? 2 : 1][4][16][72];  // per-tile

    const int lane = threadIdx.x & 63;
    const int wid  = threadIdx.x >> 6;
    const int l15  = lane & 15;
    const int grp  = lane >> 4;                       // 0..3
    const int block0 = blockIdx.x * 128;

    // --- issue ALL loads for both tiles up front (MLP) ---
    int tb[2], sv[2], dv[2];
    #pragma unroll
    for (int tt = 0; tt < 2; tt++) {
        tb[tt] = block0 + tt * 64 + wid * 16;
        sv[tt] = src[tb[tt] + l15];
        dv[tt] = dst[tb[tt] + l15];
    }

    u16x8 ga[2][2], gb[2][2];
    #pragma unroll
    for (int tt = 0; tt < 2; tt++) {
        #pragma unroll
        for (int it = 0; it < 2; it++) {
            const int row = it * 8 + (lane >> 3);     // 0..15
            const int c8 = (lane & 7) * 8;
            const int s = __shfl(sv[tt], row, 16);
            const int d = __shfl(dv[tt], row, 16);
            ga[tt][it] = *reinterpret_cast<const u16x8*>(fni + (u32)(s * FE + c8));
            gb[tt][it] = *reinterpret_cast<const u16x8*>(fnj + (u32)(d * FE + c8));
        }
    }

    bf16x8 afr[2][2];       // [tile][half]
    #pragma unroll
    for (int tt = 0; tt < 2; tt++) {
        if constexpr (FIRST) {
            const float2 xx = *reinterpret_cast<const float2*>(x + 2 * (u32)(tb[tt] + l15));
            #pragma unroll
            for (int half = 0; half < 2; half++) {
                const int c0 = half * 32 + grp * 8;
                const float4 wA0 = *reinterpret_cast<const float4*>(Win + c0);
                const float4 wA1 = *reinterpret_cast<const float4*>(Win + c0 + 4);
                const float4 wB0 = *reinterpret_cast<const float4*>(Win + FE + c0);
                const float4 wB1 = *reinterpret_cast<const float4*>(Win + FE + c0 + 4);
                const float4 b0  = *reinterpret_cast<const float4*>(bin + c0);
                const float4 b1  = *reinterpret_cast<const float4*>(bin + c0 + 4);
                u32x4 fr;
                fr[0] = cvt2bf(fmaf(xx.x, wA0.x, fmaf(xx.y, wB0.x, b0.x)),
                               fmaf(xx.x, wA0.y, fmaf(xx.y, wB0.y, b0.y)));
                fr[1] = cvt2bf(fmaf(xx.x, wA0.z, fmaf(xx.y, wB0.z, b0.z)),
                               fmaf(xx.x, wA0.w, fmaf(xx.y, wB0.w, b0.w)));
                fr[2] = cvt2bf(fmaf(xx.x, wA1.x, fmaf(xx.y, wB1.x, b1.x)),
                               fmaf(xx.x, wA1.y, fmaf(xx.y, wB1.y, b1.y)));
                fr[3] = cvt2bf(fmaf(xx.x, wA1.z, fmaf(xx.y, wB1.z, b1.z)),
                               fmaf(xx.x, wA1.w, fmaf(xx.y, wB1.w, b1.w)));
                afr[tt][half] = (bf16x8)fr;
            }
        } else {
            const u32 arow = (u32)(tb[tt] + l15) * FE;
            afr[tt][0] = *reinterpret_cast<const bf16x8*>(ef + arow + grp * 8);
            afr[tt][1] = *reinterpret_cast<const bf16x8*>(ef + arow + 32 + grp * 8);
        }
    }

    // --- B fragments: Wt[n][k]; n = nt*16+l15, k = ks*32+grp*8+j ---
    bf16x8 bfr[2][4];
    #pragma unroll
    for (int ks = 0; ks < 2; ks++)
        #pragma unroll
        for (int nt = 0; nt < 4; nt++)
            bfr[ks][nt] = *reinterpret_cast<const bf16x8*>(
                Wt + (u32)((nt * 16 + l15) * 64 + ks * 32 + grp * 8));

    float an[4];
    #pragma unroll
    for (int nt = 0; nt < 4; nt++) an[nt] = attn[nt * 16 + l15] * 1.44269504088896f;

    // --- BOTH tiles' stage writes (independent buffers) ---
    #pragma unroll
    for (int tt = 0; tt < 2; tt++) {
        #pragma unroll
        for (int it = 0; it < 2; it++) {
            const int row = it * 8 + (lane >> 3);
            const int c8 = (lane & 7) * 8;
            u32x4 s;
            #pragma unroll
            for (int j = 0; j < 4; j++) {
                s[j] = cvt2bf(bf2f(ga[tt][it][2*j])   + bf2f(gb[tt][it][2*j]),
                              bf2f(ga[tt][it][2*j+1]) + bf2f(gb[tt][it][2*j+1]));
            }
            *reinterpret_cast<u32x4*>(&stage[tt][wid][row][c8]) = s;
        }
    }

    // --- BOTH tiles' MFMAs ---
    f32x4 acc[2][4];
    #pragma unroll
    for (int tt = 0; tt < 2; tt++) {
        #pragma unroll
        for (int nt = 0; nt < 4; nt++) {
            acc[tt][nt] = (f32x4){0.f, 0.f, 0.f, 0.f};
            acc[tt][nt] = __builtin_amdgcn_mfma_f32_16x16x32_bf16(afr[tt][0], bfr[0][nt], acc[tt][nt], 0, 0, 0);
            acc[tt][nt] = __builtin_amdgcn_mfma_f32_16x16x32_bf16(afr[tt][1], bfr[1][nt], acc[tt][nt], 0, 0, 0);
        }
    }

    __builtin_amdgcn_wave_barrier();   // stage writes <-> epilogue reads

    // --- BOTH epilogues: staged add, leaky_relu, logit, fol write, scatter ---
    #pragma unroll
    for (int tt = 0; tt < 2; tt++) {
        float logit[4] = {0.f, 0.f, 0.f, 0.f};
        #pragma unroll
        for (int nt = 0; nt < 4; nt++) {
            const int n = nt * 16 + l15;
            #pragma unroll
            for (int r = 0; r < 4; r++) {
                const int row = grp * 4 + r;          // edge slot in wave
                float v = acc[tt][nt][r] + bf2f(stage[tt][wid][row][n]);
                v = fmaxf(v, 0.2f * v);               // leaky_relu(0.2)
                logit[r] = fmaf(v, an[nt], logit[r]);
                if constexpr (WRITE_EF) fol[tt][wid][row][n] = f2bf(v);
            }
        }
        #pragma unroll
        for (int r = 0; r < 4; r++) {
            float t = logit[r];
            t += __shfl_xor(t, 1, 16);
            t += __shfl_xor(t, 2, 16);
            t += __shfl_xor(t, 4, 16);
            t += __shfl_xor(t, 8, 16);
            const int sidx = __shfl(sv[tt], grp * 4 + r, 16);
            const int didx = __shfl(dv[tt], grp * 4 + r, 16);
            if (l15 == 0) {
                atomicAdd(S + (u32)(didx * N_NODES + sidx), exp2f(t));
            }
        }
    }

    // --- BOTH write-backs from A-frag registers + fol LDS ---
    if constexpr (WRITE_EF) {
        __builtin_amdgcn_wave_barrier();   // fol writes <-> fol reads
        #pragma unroll
        for (int tt = 0; tt < 2; tt++) {
            const u16x8 fo0 = *reinterpret_cast<const u16x8*>(&fol[tt][wid][l15][grp * 8]);
            const u16x8 fo1 = *reinterpret_cast<const u16x8*>(&fol[tt][wid][l15][32 + grp * 8]);
            u32x4 o0, o1;
            #pragma unroll
            for (int j = 0; j < 4; j++) {
                o0[j] = cvt2bf(bf2f((u16)afr[tt][0][2*j])   + bf2f(fo0[2*j]),
                               bf2f((u16)afr[tt][0][2*j+1]) + bf2f(fo0[2*j+1]));
                o1[j] = cvt2bf(bf2f((u16)afr[tt][1][2*j])   + bf2f(fo1[2*j]),
                               bf2f((u16)afr[tt][1][2*j+1]) + bf2f(fo1[2*j+1]));
            }
            u16* gp = ef + (u32)(tb[tt] + l15) * FE;
            *reinterpret_cast<u32x4*>(gp + grp * 8) = o0;
            *reinterpret_cast<u32x4*>(gp + 32 + grp * 8) = o1;
        }
    }
}

// ---------------------------------------------------------------------------
// spmm (1024 blocks, 1 dst row each; h bf16). nout = nin + (S@h)/rowsum(S).
// For !LAST: re-zero S row, write nodeA, next-layer projections (h dbuf).
// ---------------------------------------------------------------------------
template <bool LAST>
__global__ __launch_bounds__(256) void spmm_kernel(
    float* __restrict__ S, const u16* __restrict__ h,
    const float* __restrict__ nin, float* __restrict__ nout,
    const float* __restrict__ Wni, const float* __restrict__ Wnj,
    const float* __restrict__ Wnode, const float* __restrict__ bias,
    u16* __restrict__ fni, u16* __restrict__ fnj, u16* __restrict__ hnext)
{
    __shared__ float red[256];
    __shared__ float rs[2];
    __shared__ float row[FC];
    const int d = blockIdx.x;
    const int t = threadIdx.x;
    const int c = t & 127;
    const int half = t >> 7;
    const float* Srow = S + (u32)d * N_NODES + half * 512;
    const u16* hp = h + (u32)(half * 512 * FC);
    float a0 = 0.f, a1 = 0.f, a2 = 0.f, a3 = 0.f;
    float r0 = 0.f, r1 = 0.f, r2 = 0.f, r3 = 0.f;
    #pragma unroll 4
    for (int n = 0; n < 512; n += 4) {
        const float s0 = Srow[n], s1 = Srow[n+1], s2 = Srow[n+2], s3 = Srow[n+3];
        r0 += s0; r1 += s1; r2 += s2; r3 += s3;
        a0 = fmaf(s0, bf2f(hp[n * FC + c]), a0);
        a1 = fmaf(s1, bf2f(hp[(n+1) * FC + c]), a1);
        a2 = fmaf(s2, bf2f(hp[(n+2) * FC + c]), a2);
        a3 = fmaf(s3, bf2f(hp[(n+3) * FC + c]), a3);
    }
    red[t] = (a0 + a1) + (a2 + a3);
    if (c == 0) rs[half] = (r0 + r1) + (r2 + r3);
    __syncthreads();

    if constexpr (!LAST) {   // re-zero S row for next layer (reads done)
        reinterpret_cast<float4*>(S + (u32)d * N_NODES)[t] = make_float4(0.f, 0.f, 0.f, 0.f);
    }
    if (half == 0) {
        const float v = nin[d * FC + c] + (red[c] + red[128 + c]) / (rs[0] + rs[1]);
        nout[d * FC + c] = v;
        if constexpr (!LAST) row[c] = v;
    }

    if constexpr (!LAST) {
        __syncthreads();
        if (t < 64) {
            float b0 = 0.f, b1 = 0.f;
            #pragma unroll 8
            for (int k = 0; k < FC; k += 2) {
                b0 = fmaf(row[k],     Wni[k * FE + t], b0);
                b1 = fmaf(row[k + 1], Wni[(k + 1) * FE + t], b1);
            }
            fni[d * FE + t] = f2bf(b0 + b1);
        } else if (t < 128) {
            const int f = t - 64;
            float b0 = 0.f, b1 = 0.f;
            #pragma unroll 8
            for (int k = 0; k < FC; k += 2) {
                b0 = fmaf(row[k],     Wnj[k * FE + f], b0);
                b1 = fmaf(row[k + 1], Wnj[(k + 1) * FE + f], b1);
            }
            fnj[d * FE + f] = f2bf(b0 + b1);
        } else {
            const int cc = t - 128;
            float b0 = bias[cc], b1 = 0.f;
            #pragma unroll 8
            for (int k = 0; k < FC; k += 2) {
                b0 = fmaf(row[k],     Wnode[k * FC + cc], b0);
                b1 = fmaf(row[k + 1], Wnode[(k + 1) * FC + cc], b1);
            }
            hnext[d * FC + cc] = f2bf(b0 + b1);
        }
    }
}

// ---------------------------------------------------------------------------
extern "C" void kernel_launch(void* const* d_in, const int* in_sizes, int n_in,
                              void* d_out, int out_size, void* d_ws, size_t ws_size,
                              hipStream_t stream)
{
    const float* node_feature = (const float*)d_in[0];
    const float* edge_feature = (const float*)d_in[1];
    const int*   src          = (const int*)d_in[2];
    const int*   dst          = (const int*)d_in[3];
    const float* W_in         = (const float*)d_in[4];
    const float* b_in         = (const float*)d_in[5];
    const float* W_ni         = (const float*)d_in[6];
    const float* W_nj         = (const float*)d_in[7];
    const float* W_fij        = (const float*)d_in[8];
    const float* W_node       = (const float*)d_in[9];
    const float* attn         = (const float*)d_in[10];
    const float* bias_node    = (const float*)d_in[11];
    float* out = (float*)d_out;

    char* ws = (char*)d_ws;
    size_t off = 0;
    auto alloc = [&](size_t bytes) -> void* {
        void* pp = ws + off;
        off += (bytes + 255) & ~(size_t)255;
        return pp;
    };
    u16*   ef    = (u16*)alloc((size_t)E_EDGES * FE * sizeof(u16));       // 67 MB
    u16*   fni   = (u16*)alloc(N_NODES * FE * sizeof(u16));
    u16*   fnj   = (u16*)alloc(N_NODES * FE * sizeof(u16));
    u16*   h0    = (u16*)alloc(N_NODES * FC * sizeof(u16));
    u16*   h1    = (u16*)alloc(N_NODES * FC * sizeof(u16));
    float* S     = (float*)alloc((size_t)N_NODES * N_NODES * sizeof(float)); // 4 MB
    float* nodeA = (float*)alloc(N_NODES * FC * sizeof(float));
    u16*   Wt    = (u16*)alloc((size_t)NLAYERS * FE * FE * sizeof(u16));  // 24 KB
    u16*   hbuf[2] = {h0, h1};

    setup_kernel<<<N_NODES, 256, 0, stream>>>(
        node_feature, W_fij, Wt, W_ni, W_nj, W_node, bias_node,
        fni, fnj, h0, S, nodeA);

    for (int l = 0; l < NLAYERS; l++) {
        u16* hl = hbuf[l & 1];
        u16* hn = hbuf[(l + 1) & 1];

        if (l == 0) {
            edge_mfma_kernel<true, true><<<E_EDGES / 128, 256, 0, stream>>>(
                ef, edge_feature, W_in, b_in, Wt + (size_t)l * FE * FE,
                fni, fnj, src, dst, attn + (size_t)l * FE, S);
        } else if (l == NLAYERS - 1) {
            edge_mfma_kernel<false, false><<<E_EDGES / 128, 256, 0, stream>>>(
                ef, nullptr, nullptr, nullptr, Wt + (size_t)l * FE * FE,
                fni, fnj, src, dst, attn + (size_t)l * FE, S);
        } else {
            edge_mfma_kernel<false, true><<<E_EDGES / 128, 256, 0, stream>>>(
                ef, nullptr, nullptr, nullptr, Wt + (size_t)l * FE * FE,
                fni, fnj, src, dst, attn + (size_t)l * FE, S);
        }

        if (l == NLAYERS - 1) {
            spmm_kernel<true><<<N_NODES, 256, 0, stream>>>(
                S, hl, nodeA, out,
                nullptr, nullptr, nullptr, nullptr, nullptr, nullptr, nullptr);
        } else {
            const int ln = l + 1;
            spmm_kernel<false><<<N_NODES, 256, 0, stream>>>(
                S, hl, nodeA, nodeA,
                W_ni + (size_t)ln * FC * FE, W_nj + (size_t)ln * FC * FE,
                W_node + (size_t)ln * FC * FC, bias_node + (size_t)ln * FC,
                fni, fnj, hn);
        }
    }
}

// Round 17
// 232.377 us; speedup vs baseline: 1.0685x; 1.0685x over previous
//
#include <hip/hip_runtime.h>

#define N_NODES 1024
#define E_EDGES 524288
#define FE 64
#define FC 128
#define NLAYERS 3

typedef unsigned short u16;
typedef unsigned int u32;
typedef __attribute__((ext_vector_type(8))) short bf16x8;   // MFMA A/B frag
typedef __attribute__((ext_vector_type(4))) float f32x4;    // MFMA C/D frag
typedef __attribute__((ext_vector_type(8))) unsigned short u16x8;
typedef __attribute__((ext_vector_type(4))) unsigned int u32x4;

__device__ __forceinline__ float bf2f(u16 u) {
    return __uint_as_float(((u32)u) << 16);
}
__device__ __forceinline__ u32 cvt2bf(float lo, float hi) {
    u32 r;
    asm("v_cvt_pk_bf16_f32 %0, %1, %2" : "=v"(r) : "v"(lo), "v"(hi));
    return r;
}
__device__ __forceinline__ u16 f2bf(float f) {
    return (u16)cvt2bf(f, 0.f);
}

// ---------------------------------------------------------------------------
// Setup (1024 blocks, one per node): zero S row, copy node->nodeA, transpose
// W_fij into bf16 Wt (blocks 0..47), and layer-0 projections fni/fnj/h.
// ---------------------------------------------------------------------------
__global__ __launch_bounds__(256) void setup_kernel(
    const float* __restrict__ node_feature, const float* __restrict__ Wfij,
    u16* __restrict__ Wt,
    const float* __restrict__ Wni, const float* __restrict__ Wnj,
    const float* __restrict__ Wnode, const float* __restrict__ bias,
    u16* __restrict__ fni, u16* __restrict__ fnj,
    u16* __restrict__ h, float* __restrict__ S, float* __restrict__ nodeA)
{
    __shared__ float row[FC];
    const int d = blockIdx.x;
    const int t = threadIdx.x;

    reinterpret_cast<float4*>(S + (size_t)d * N_NODES)[t] = make_float4(0.f, 0.f, 0.f, 0.f);

    if (t < FC) {
        const float v = node_feature[d * FC + t];
        nodeA[d * FC + t] = v;
        row[t] = v;
    }
    if (d < (NLAYERS * FE * FE) / 256) {
        const int i = d * 256 + t;
        const int l = i >> 12, rem = i & 4095;
        const int n = rem >> 6, k = rem & 63;
        Wt[(u32)(l * 4096 + n * 64 + k)] = f2bf(Wfij[(u32)(l * 4096 + k * 64 + n)]);
    }
    __syncthreads();

    if (t < 64) {
        float a0 = 0.f, a1 = 0.f;
        #pragma unroll 8
        for (int k = 0; k < FC; k += 2) {
            a0 = fmaf(row[k],     Wni[k * FE + t], a0);
            a1 = fmaf(row[k + 1], Wni[(k + 1) * FE + t], a1);
        }
        fni[d * FE + t] = f2bf(a0 + a1);
    } else if (t < 128) {
        const int f = t - 64;
        float a0 = 0.f, a1 = 0.f;
        #pragma unroll 8
        for (int k = 0; k < FC; k += 2) {
            a0 = fmaf(row[k],     Wnj[k * FE + f], a0);
            a1 = fmaf(row[k + 1], Wnj[(k + 1) * FE + f], a1);
        }
        fnj[d * FE + f] = f2bf(a0 + a1);
    } else {
        const int c = t - 128;
        float a0 = bias[c], a1 = 0.f;
        #pragma unroll 8
        for (int k = 0; k < FC; k += 2) {
            a0 = fmaf(row[k],     Wnode[k * FC + c], a0);
            a1 = fmaf(row[k + 1], Wnode[(k + 1) * FC + c], a1);
        }
        h[d * FC + c] = f2bf(a0 + a1);
    }
}

// ---------------------------------------------------------------------------
// MFMA edge kernel, 2-TILE PIPELINED (r15 final). Block = 4 waves x 2 tiles
// of 16 edges (grid E/128). All loads for both tiles issued up front (2x
// MLP). stage/fol LDS reused across tiles, wave-local, wave_barrier-pinned.
// sidx/didx shuffles exec-full (r11 lesson: no shfl in divergent branches).
// Structure notes (hard-won):
//  - 4-tile register staging spills (allocator pins at 64 VGPR) — r14.
//  - merged dbuf-LDS single-barrier variant de-pipelines loads (VGPR 44,
//    +10% dur) — r16. The serialized 2-tile loop IS the optimum found.
//  - zero-LDS per-lane-gather variant: 2x worse VMEM behavior — r8.
// Fragment layouts (m89 family):
//   A: row=lane&15 (edge), k=(lane>>4)*8+j     B: col=lane&15 (n), same k
//   C: col=lane&15 (n),  row=(lane>>4)*4+reg   (edge)
// ---------------------------------------------------------------------------
template <bool FIRST, bool WRITE_EF>
__global__ void edge_mfma_kernel(
    u16* __restrict__ ef,                 // [E][64] bf16 (in/out)
    const float* __restrict__ x,          // [E][2]   (FIRST only)
    const float* __restrict__ Win,        // [2][64]  (FIRST only)
    const float* __restrict__ bin,        // [64]     (FIRST only)
    const u16* __restrict__ Wt,           // [64 n][64 k] bf16 (this layer)
    const u16* __restrict__ fni, const u16* __restrict__ fnj,
    const int* __restrict__ src, const int* __restrict__ dst,
    const float* __restrict__ attn,       // [64] fp32
    float* __restrict__ S)                // [N][N] fp32 (pre-zeroed)
{
    __shared__ __align__(16) u16 stage[4][16][72];               // fni+fnj sum
    __shared__ __align__(16) u16 fol[WRITE_EF ? 4 : 1][16][72];  // f_out rows

    const int lane = threadIdx.x & 63;
    const int wid  = threadIdx.x >> 6;
    const int l15  = lane & 15;
    const int grp  = lane >> 4;                       // 0..3
    const int block0 = blockIdx.x * 128;

    // --- issue ALL loads for both tiles up front (MLP) ---
    int tb[2], sv[2], dv[2];
    #pragma unroll
    for (int tt = 0; tt < 2; tt++) {
        tb[tt] = block0 + tt * 64 + wid * 16;
        sv[tt] = src[tb[tt] + l15];
        dv[tt] = dst[tb[tt] + l15];
    }

    u16x8 ga[2][2], gb[2][2];
    #pragma unroll
    for (int tt = 0; tt < 2; tt++) {
        #pragma unroll
        for (int it = 0; it < 2; it++) {
            const int row = it * 8 + (lane >> 3);     // 0..15
            const int c8 = (lane & 7) * 8;
            const int s = __shfl(sv[tt], row, 16);
            const int d = __shfl(dv[tt], row, 16);
            ga[tt][it] = *reinterpret_cast<const u16x8*>(fni + (u32)(s * FE + c8));
            gb[tt][it] = *reinterpret_cast<const u16x8*>(fnj + (u32)(d * FE + c8));
        }
    }

    bf16x8 afr[2][2];       // [tile][half]
    #pragma unroll
    for (int tt = 0; tt < 2; tt++) {
        if constexpr (FIRST) {
            const float2 xx = *reinterpret_cast<const float2*>(x + 2 * (u32)(tb[tt] + l15));
            #pragma unroll
            for (int half = 0; half < 2; half++) {
                const int c0 = half * 32 + grp * 8;
                const float4 wA0 = *reinterpret_cast<const float4*>(Win + c0);
                const float4 wA1 = *reinterpret_cast<const float4*>(Win + c0 + 4);
                const float4 wB0 = *reinterpret_cast<const float4*>(Win + FE + c0);
                const float4 wB1 = *reinterpret_cast<const float4*>(Win + FE + c0 + 4);
                const float4 b0  = *reinterpret_cast<const float4*>(bin + c0);
                const float4 b1  = *reinterpret_cast<const float4*>(bin + c0 + 4);
                u32x4 fr;
                fr[0] = cvt2bf(fmaf(xx.x, wA0.x, fmaf(xx.y, wB0.x, b0.x)),
                               fmaf(xx.x, wA0.y, fmaf(xx.y, wB0.y, b0.y)));
                fr[1] = cvt2bf(fmaf(xx.x, wA0.z, fmaf(xx.y, wB0.z, b0.z)),
                               fmaf(xx.x, wA0.w, fmaf(xx.y, wB0.w, b0.w)));
                fr[2] = cvt2bf(fmaf(xx.x, wA1.x, fmaf(xx.y, wB1.x, b1.x)),
                               fmaf(xx.x, wA1.y, fmaf(xx.y, wB1.y, b1.y)));
                fr[3] = cvt2bf(fmaf(xx.x, wA1.z, fmaf(xx.y, wB1.z, b1.z)),
                               fmaf(xx.x, wA1.w, fmaf(xx.y, wB1.w, b1.w)));
                afr[tt][half] = (bf16x8)fr;
            }
        } else {
            const u32 arow = (u32)(tb[tt] + l15) * FE;
            afr[tt][0] = *reinterpret_cast<const bf16x8*>(ef + arow + grp * 8);
            afr[tt][1] = *reinterpret_cast<const bf16x8*>(ef + arow + 32 + grp * 8);
        }
    }

    // --- B fragments: Wt[n][k]; n = nt*16+l15, k = ks*32+grp*8+j ---
    bf16x8 bfr[2][4];
    #pragma unroll
    for (int ks = 0; ks < 2; ks++)
        #pragma unroll
        for (int nt = 0; nt < 4; nt++)
            bfr[ks][nt] = *reinterpret_cast<const bf16x8*>(
                Wt + (u32)((nt * 16 + l15) * 64 + ks * 32 + grp * 8));

    float an[4];
    #pragma unroll
    for (int nt = 0; nt < 4; nt++) an[nt] = attn[nt * 16 + l15] * 1.44269504088896f;

    // --- process tiles sequentially, reusing stage/fol ---
    #pragma unroll
    for (int tt = 0; tt < 2; tt++) {
        #pragma unroll
        for (int it = 0; it < 2; it++) {
            const int row = it * 8 + (lane >> 3);
            const int c8 = (lane & 7) * 8;
            u32x4 s;
            #pragma unroll
            for (int j = 0; j < 4; j++) {
                s[j] = cvt2bf(bf2f(ga[tt][it][2*j])   + bf2f(gb[tt][it][2*j]),
                              bf2f(ga[tt][it][2*j+1]) + bf2f(gb[tt][it][2*j+1]));
            }
            *reinterpret_cast<u32x4*>(&stage[wid][row][c8]) = s;
        }

        f32x4 acc[4];
        #pragma unroll
        for (int nt = 0; nt < 4; nt++) {
            acc[nt] = (f32x4){0.f, 0.f, 0.f, 0.f};
            acc[nt] = __builtin_amdgcn_mfma_f32_16x16x32_bf16(afr[tt][0], bfr[0][nt], acc[nt], 0, 0, 0);
            acc[nt] = __builtin_amdgcn_mfma_f32_16x16x32_bf16(afr[tt][1], bfr[1][nt], acc[nt], 0, 0, 0);
        }

        __builtin_amdgcn_wave_barrier();   // stage writes <-> epilogue reads

        float logit[4] = {0.f, 0.f, 0.f, 0.f};
        #pragma unroll
        for (int nt = 0; nt < 4; nt++) {
            const int n = nt * 16 + l15;
            #pragma unroll
            for (int r = 0; r < 4; r++) {
                const int row = grp * 4 + r;          // edge slot in wave
                float v = acc[nt][r] + bf2f(stage[wid][row][n]);
                v = fmaxf(v, 0.2f * v);               // leaky_relu(0.2)
                logit[r] = fmaf(v, an[nt], logit[r]);
                if constexpr (WRITE_EF) fol[wid][row][n] = f2bf(v);
            }
        }

        // logit reduce (16 lanes/edge) + direct scatter into S
        #pragma unroll
        for (int r = 0; r < 4; r++) {
            float t = logit[r];
            t += __shfl_xor(t, 1, 16);
            t += __shfl_xor(t, 2, 16);
            t += __shfl_xor(t, 4, 16);
            t += __shfl_xor(t, 8, 16);
            const int sidx = __shfl(sv[tt], grp * 4 + r, 16);
            const int didx = __shfl(dv[tt], grp * 4 + r, 16);
            if (l15 == 0) {
                atomicAdd(S + (u32)(didx * N_NODES + sidx), exp2f(t));
            }
        }

        if constexpr (WRITE_EF) {
            __builtin_amdgcn_wave_barrier();   // fol writes <-> fol reads
            const u16x8 fo0 = *reinterpret_cast<const u16x8*>(&fol[wid][l15][grp * 8]);
            const u16x8 fo1 = *reinterpret_cast<const u16x8*>(&fol[wid][l15][32 + grp * 8]);
            u32x4 o0, o1;
            #pragma unroll
            for (int j = 0; j < 4; j++) {
                o0[j] = cvt2bf(bf2f((u16)afr[tt][0][2*j])   + bf2f(fo0[2*j]),
                               bf2f((u16)afr[tt][0][2*j+1]) + bf2f(fo0[2*j+1]));
                o1[j] = cvt2bf(bf2f((u16)afr[tt][1][2*j])   + bf2f(fo1[2*j]),
                               bf2f((u16)afr[tt][1][2*j+1]) + bf2f(fo1[2*j+1]));
            }
            u16* gp = ef + (u32)(tb[tt] + l15) * FE;
            *reinterpret_cast<u32x4*>(gp + grp * 8) = o0;
            *reinterpret_cast<u32x4*>(gp + 32 + grp * 8) = o1;
        }

        __builtin_amdgcn_wave_barrier();   // protect stage/fol reuse by tile 1
    }
}

// ---------------------------------------------------------------------------
// spmm (1024 blocks, 1 dst row each; h bf16). nout = nin + (S@h)/rowsum(S).
// For !LAST: re-zero S row, write nodeA, next-layer projections (h dbuf).
// (r11's 4-rows-per-block variant regressed to 53 µs at 1 block/CU —
// occupancy beats traffic-saving for L2-resident h.)
// ---------------------------------------------------------------------------
template <bool LAST>
__global__ __launch_bounds__(256) void spmm_kernel(
    float* __restrict__ S, const u16* __restrict__ h,
    const float* __restrict__ nin, float* __restrict__ nout,
    const float* __restrict__ Wni, const float* __restrict__ Wnj,
    const float* __restrict__ Wnode, const float* __restrict__ bias,
    u16* __restrict__ fni, u16* __restrict__ fnj, u16* __restrict__ hnext)
{
    __shared__ float red[256];
    __shared__ float rs[2];
    __shared__ float row[FC];
    const int d = blockIdx.x;
    const int t = threadIdx.x;
    const int c = t & 127;
    const int half = t >> 7;
    const float* Srow = S + (u32)d * N_NODES + half * 512;
    const u16* hp = h + (u32)(half * 512 * FC);
    float a0 = 0.f, a1 = 0.f, a2 = 0.f, a3 = 0.f;
    float r0 = 0.f, r1 = 0.f, r2 = 0.f, r3 = 0.f;
    #pragma unroll 4
    for (int n = 0; n < 512; n += 4) {
        const float s0 = Srow[n], s1 = Srow[n+1], s2 = Srow[n+2], s3 = Srow[n+3];
        r0 += s0; r1 += s1; r2 += s2; r3 += s3;
        a0 = fmaf(s0, bf2f(hp[n * FC + c]), a0);
        a1 = fmaf(s1, bf2f(hp[(n+1) * FC + c]), a1);
        a2 = fmaf(s2, bf2f(hp[(n+2) * FC + c]), a2);
        a3 = fmaf(s3, bf2f(hp[(n+3) * FC + c]), a3);
    }
    red[t] = (a0 + a1) + (a2 + a3);
    if (c == 0) rs[half] = (r0 + r1) + (r2 + r3);
    __syncthreads();

    if constexpr (!LAST) {   // re-zero S row for next layer (reads done)
        reinterpret_cast<float4*>(S + (u32)d * N_NODES)[t] = make_float4(0.f, 0.f, 0.f, 0.f);
    }
    if (half == 0) {
        const float v = nin[d * FC + c] + (red[c] + red[128 + c]) / (rs[0] + rs[1]);
        nout[d * FC + c] = v;
        if constexpr (!LAST) row[c] = v;
    }

    if constexpr (!LAST) {
        __syncthreads();
        if (t < 64) {
            float b0 = 0.f, b1 = 0.f;
            #pragma unroll 8
            for (int k = 0; k < FC; k += 2) {
                b0 = fmaf(row[k],     Wni[k * FE + t], b0);
                b1 = fmaf(row[k + 1], Wni[(k + 1) * FE + t], b1);
            }
            fni[d * FE + t] = f2bf(b0 + b1);
        } else if (t < 128) {
            const int f = t - 64;
            float b0 = 0.f, b1 = 0.f;
            #pragma unroll 8
            for (int k = 0; k < FC; k += 2) {
                b0 = fmaf(row[k],     Wnj[k * FE + f], b0);
                b1 = fmaf(row[k + 1], Wnj[(k + 1) * FE + f], b1);
            }
            fnj[d * FE + f] = f2bf(b0 + b1);
        } else {
            const int cc = t - 128;
            float b0 = bias[cc], b1 = 0.f;
            #pragma unroll 8
            for (int k = 0; k < FC; k += 2) {
                b0 = fmaf(row[k],     Wnode[k * FC + cc], b0);
                b1 = fmaf(row[k + 1], Wnode[(k + 1) * FC + cc], b1);
            }
            hnext[d * FC + cc] = f2bf(b0 + b1);
        }
    }
}

// ---------------------------------------------------------------------------
extern "C" void kernel_launch(void* const* d_in, const int* in_sizes, int n_in,
                              void* d_out, int out_size, void* d_ws, size_t ws_size,
                              hipStream_t stream)
{
    const float* node_feature = (const float*)d_in[0];
    const float* edge_feature = (const float*)d_in[1];
    const int*   src          = (const int*)d_in[2];
    const int*   dst          = (const int*)d_in[3];
    const float* W_in         = (const float*)d_in[4];
    const float* b_in         = (const float*)d_in[5];
    const float* W_ni         = (const float*)d_in[6];
    const float* W_nj         = (const float*)d_in[7];
    const float* W_fij        = (const float*)d_in[8];
    const float* W_node       = (const float*)d_in[9];
    const float* attn         = (const float*)d_in[10];
    const float* bias_node    = (const float*)d_in[11];
    float* out = (float*)d_out;

    char* ws = (char*)d_ws;
    size_t off = 0;
    auto alloc = [&](size_t bytes) -> void* {
        void* pp = ws + off;
        off += (bytes + 255) & ~(size_t)255;
        return pp;
    };
    u16*   ef    = (u16*)alloc((size_t)E_EDGES * FE * sizeof(u16));       // 67 MB
    u16*   fni   = (u16*)alloc(N_NODES * FE * sizeof(u16));
    u16*   fnj   = (u16*)alloc(N_NODES * FE * sizeof(u16));
    u16*   h0    = (u16*)alloc(N_NODES * FC * sizeof(u16));
    u16*   h1    = (u16*)alloc(N_NODES * FC * sizeof(u16));
    float* S     = (float*)alloc((size_t)N_NODES * N_NODES * sizeof(float)); // 4 MB
    float* nodeA = (float*)alloc(N_NODES * FC * sizeof(float));
    u16*   Wt    = (u16*)alloc((size_t)NLAYERS * FE * FE * sizeof(u16));  // 24 KB
    u16*   hbuf[2] = {h0, h1};

    setup_kernel<<<N_NODES, 256, 0, stream>>>(
        node_feature, W_fij, Wt, W_ni, W_nj, W_node, bias_node,
        fni, fnj, h0, S, nodeA);

    for (int l = 0; l < NLAYERS; l++) {
        u16* hl = hbuf[l & 1];
        u16* hn = hbuf[(l + 1) & 1];

        if (l == 0) {
            edge_mfma_kernel<true, true><<<E_EDGES / 128, 256, 0, stream>>>(
                ef, edge_feature, W_in, b_in, Wt + (size_t)l * FE * FE,
                fni, fnj, src, dst, attn + (size_t)l * FE, S);
        } else if (l == NLAYERS - 1) {
            edge_mfma_kernel<false, false><<<E_EDGES / 128, 256, 0, stream>>>(
                ef, nullptr, nullptr, nullptr, Wt + (size_t)l * FE * FE,
                fni, fnj, src, dst, attn + (size_t)l * FE, S);
        } else {
            edge_mfma_kernel<false, true><<<E_EDGES / 128, 256, 0, stream>>>(
                ef, nullptr, nullptr, nullptr, Wt + (size_t)l * FE * FE,
                fni, fnj, src, dst, attn + (size_t)l * FE, S);
        }

        if (l == NLAYERS - 1) {
            spmm_kernel<true><<<N_NODES, 256, 0, stream>>>(
                S, hl, nodeA, out,
                nullptr, nullptr, nullptr, nullptr, nullptr, nullptr, nullptr);
        } else {
            const int ln = l + 1;
            spmm_kernel<false><<<N_NODES, 256, 0, stream>>>(
                S, hl, nodeA, nodeA,
                W_ni + (size_t)ln * FC * FE, W_nj + (size_t)ln * FC * FE,
                W_node + (size_t)ln * FC * FC, bias_node + (size_t)ln * FC,
                fni, fnj, hn);
        }
    }
}